// Round 5
// baseline (12284.869 us; speedup 1.0000x reference)
//
#include <hip/hip_runtime.h>

constexpr int Dm = 128;     // dims
constexpr int D4 = 32;      // dims/4
constexpr int Kc = 64;      // clusters
constexpr int NITER = 10;
constexpr double TOLd = 1e-4;
constexpr int BT  = 256;
constexpr int SLC = 256;    // slices for gather-sum (1 block/CU, 128KB LDS acc)
constexpr int PPB = 128;    // points per block in assign
constexpr float MARGIN = 1e-2f;   // fp32 top-2 gap below which we re-check in fp64

// ---- argmax helpers: exact total order (value desc, index asc) => deterministic ----
__device__ __forceinline__ void wave_argmax(double& bd, int& bi) {
#pragma unroll
  for (int off = 32; off; off >>= 1) {
    double od = __shfl_down(bd, (unsigned)off, 64);
    int    oi = __shfl_down(bi, (unsigned)off, 64);
    if (od > bd || (od == bd && oi < bi)) { bd = od; bi = oi; }
  }
}

// 256-thread block argmax; wd/wi are 4-entry LDS scratch
__device__ __forceinline__ void block_argmax(double& bd, int& bi, double* wd, int* wi) {
  wave_argmax(bd, bi);
  const int w = threadIdx.x >> 6;
  if ((threadIdx.x & 63) == 0) { wd[w] = bd; wi[w] = bi; }
  __syncthreads();
  bd = wd[0]; bi = wi[0];
#pragma unroll
  for (int j = 1; j < 4; ++j) {
    double od = wd[j]; int oi = wi[j];
    if (od > bd || (od == bd && oi < bi)) { bd = od; bi = oi; }
  }
  __syncthreads();
}

__global__ __launch_bounds__(BT) void k_init_first(
    const float* __restrict__ X, float* __restrict__ Cout, double* __restrict__ Cd,
    double* __restrict__ x2d, double* __restrict__ mind,
    double* __restrict__ opd, int* __restrict__ opi, int* __restrict__ done_flag, int N) {
  __shared__ double cent[Dm];
  __shared__ double wd[4]; __shared__ int wi[4];
  if (threadIdx.x < Dm) cent[threadIdx.x] = (double)X[threadIdx.x];
  if (blockIdx.x == 0) {
    if (threadIdx.x == 0) *done_flag = 0;
    if (threadIdx.x < Dm) {
      Cout[threadIdx.x] = X[threadIdx.x];
      Cd[threadIdx.x]   = (double)X[threadIdx.x];
    }
  }
  __syncthreads();
  double c2 = 0.0;
  for (int d = 0; d < Dm; ++d) c2 += cent[d] * cent[d];
  const int n = blockIdx.x * BT + threadIdx.x;
  double bd = -1.0; int bi = 0x7fffffff;
  if (n < N) {
    const float4* xr = (const float4*)(X + (size_t)n * Dm);
    double a0 = 0, a1 = 0, a2 = 0, a3 = 0;
    double x0 = 0, x1 = 0, x2 = 0, x3 = 0;
#pragma unroll 8
    for (int q = 0; q < D4; ++q) {
      float4 xv = xr[q];
      a0 += (double)xv.x * cent[4*q+0]; a1 += (double)xv.y * cent[4*q+1];
      a2 += (double)xv.z * cent[4*q+2]; a3 += (double)xv.w * cent[4*q+3];
      x0 += (double)xv.x * xv.x; x1 += (double)xv.y * xv.y;
      x2 += (double)xv.z * xv.z; x3 += (double)xv.w * xv.w;
    }
    double xx  = (x0 + x1) + (x2 + x3);
    double dot = (a0 + a1) + (a2 + a3);
    x2d[n] = xx;
    double d2 = c2 + xx - 2.0 * dot; if (d2 < 0.0) d2 = 0.0;
    mind[n] = d2;
    bd = d2; bi = n;
  }
  block_argmax(bd, bi, wd, wi);
  if (threadIdx.x == 0) { opd[blockIdx.x] = bd; opi[blockIdx.x] = bi; }
}

__global__ __launch_bounds__(BT) void k_init_step(
    const float* __restrict__ X, float* __restrict__ Cout, double* __restrict__ Cd,
    const double* __restrict__ x2d, double* __restrict__ mind,
    const double* __restrict__ ipd, const int* __restrict__ ipi,
    double* __restrict__ opd, int* __restrict__ opi,
    int N, int nparts, int ci, int update,
    double* __restrict__ c2d, float* __restrict__ c2f) {
  __shared__ double cent[Dm];
  __shared__ double wd[4]; __shared__ int wi[4];
  // per-wave redundant partial reduce (no barriers, exact total order)
  const int lane = threadIdx.x & 63;
  double bd = -1.0; int bi = 0x7fffffff;
  for (int t = lane; t < nparts; t += 64) {
    double d = ipd[t]; int id = ipi[t];
    if (d > bd || (d == bd && id < bi)) { bd = d; bi = id; }
  }
  wave_argmax(bd, bi);
  const int idx = __shfl(bi, 0, 64);
  if (threadIdx.x < Dm) {
    float xv = X[(size_t)idx * Dm + threadIdx.x];
    cent[threadIdx.x] = (double)xv;
    if (blockIdx.x == 0) {
      Cout[(size_t)ci * Dm + threadIdx.x] = xv;
      Cd[(size_t)ci * Dm + threadIdx.x]   = (double)xv;
    }
  }
  __syncthreads();
  if (c2d) {  // final step (single block): c2 of all rows for the Lloyd loop
    if ((int)threadIdx.x < Kc) {
      double s = 0.0;
      if ((int)threadIdx.x == ci) { for (int d = 0; d < Dm; ++d) s += cent[d] * cent[d]; }
      else { for (int d = 0; d < Dm; ++d) { double v = Cd[(size_t)threadIdx.x * Dm + d]; s += v * v; } }
      c2d[threadIdx.x] = s; c2f[threadIdx.x] = (float)s;
    }
  }
  if (!update) return;
  double c2 = 0.0;
  for (int d = 0; d < Dm; ++d) c2 += cent[d] * cent[d];
  const int n = blockIdx.x * BT + threadIdx.x;
  bd = -1.0; bi = 0x7fffffff;
  if (n < N) {
    const float4* xr = (const float4*)(X + (size_t)n * Dm);
    double a0 = 0, a1 = 0, a2 = 0, a3 = 0;
#pragma unroll 8
    for (int q = 0; q < D4; ++q) {
      float4 xv = xr[q];
      a0 += (double)xv.x * cent[4*q+0]; a1 += (double)xv.y * cent[4*q+1];
      a2 += (double)xv.z * cent[4*q+2]; a3 += (double)xv.w * cent[4*q+3];
    }
    double dot = (a0 + a1) + (a2 + a3);
    double d2 = c2 + x2d[n] - 2.0 * dot; if (d2 < 0.0) d2 = 0.0;
    double m = mind[n]; if (d2 < m) m = d2;
    mind[n] = m;
    bd = m; bi = n;
  }
  block_argmax(bd, bi, wd, wi);
  if (threadIdx.x == 0) { opd[blockIdx.x] = bd; opi[blockIdx.x] = bi; }
}

// register-tiled assign: 16 pgroups x 16 kgroups; thread = 8 points x 4 clusters.
// C transposed in LDS (broadcast-friendly), X streamed from global (L3-resident).
__global__ __launch_bounds__(256) void k_assign(
    const float* __restrict__ X, const float* __restrict__ Cf,
    const float* __restrict__ c2f, const double* __restrict__ Cd,
    const double* __restrict__ c2d,
    unsigned char* __restrict__ lbl, const int* __restrict__ done_flag, int N) {
  if (*done_flag) return;
  __shared__ float Ct[Dm * 68];    // [d][k], stride 68: kg & kg+8 2-way (free)
  __shared__ float c2s[Kc];
  const int tid = threadIdx.x;
  for (int e = tid; e < Kc * D4; e += 256) {   // lanes k-major -> conflict-free writes
    const int k = e & 63, d4 = e >> 6;
    float4 v = ((const float4*)Cf)[k * D4 + d4];
    Ct[(4*d4+0)*68 + k] = v.x; Ct[(4*d4+1)*68 + k] = v.y;
    Ct[(4*d4+2)*68 + k] = v.z; Ct[(4*d4+3)*68 + k] = v.w;
  }
  if (tid < Kc) c2s[tid] = c2f[tid];
  __syncthreads();
  const int w = tid >> 6, pg = tid >> 4, kg = tid & 15;
  const int k0 = kg * 4;
  const int pbase = blockIdx.x * PPB + 32 * w + (pg & 3);  // +4j -> 4 rows/wave-instr
  const float4* xr[8];
#pragma unroll
  for (int j = 0; j < 8; ++j) {
    int p = pbase + 4 * j; if (p > N - 1) p = N - 1;       // clamped (guard at write)
    xr[j] = (const float4*)(X + (size_t)p * Dm);
  }
  float acc[8][4];
#pragma unroll
  for (int j = 0; j < 8; ++j) { acc[j][0]=0.f; acc[j][1]=0.f; acc[j][2]=0.f; acc[j][3]=0.f; }
#pragma unroll 2
  for (int d4 = 0; d4 < D4; ++d4) {
    float cf[4][4];
#pragma unroll
    for (int i = 0; i < 4; ++i) {
      float4 cv = *(const float4*)&Ct[(4*d4+i)*68 + k0];
      cf[i][0] = cv.x; cf[i][1] = cv.y; cf[i][2] = cv.z; cf[i][3] = cv.w;
    }
#pragma unroll
    for (int j = 0; j < 8; ++j) {
      float4 xj = xr[j][d4];
#pragma unroll
      for (int c = 0; c < 4; ++c)   // d ascending via nested fma chain
        acc[j][c] = fmaf(xj.w, cf[3][c], fmaf(xj.z, cf[2][c],
                    fmaf(xj.y, cf[1][c], fmaf(xj.x, cf[0][c], acc[j][c]))));
    }
  }
#pragma unroll
  for (int j = 0; j < 8; ++j) {
    const int p = pbase + 4 * j;
    // thread-local top-2 over its 4 clusters (k ascending, strict <)
    float b = 3.4028235e38f, s = 3.4028235e38f; int bk = 0;
#pragma unroll
    for (int c = 0; c < 4; ++c) {
      float sc = c2s[k0 + c] - 2.f * acc[j][c];
      if (sc < b) { s = b; b = sc; bk = k0 + c; } else if (sc < s) s = sc;
    }
    // merge across the 16 kg-lanes: lexicographic (score, k) keeps first-index rule
#pragma unroll
    for (int m = 1; m < 16; m <<= 1) {
      float ob = __shfl_xor(b, m, 64);
      int  obk = __shfl_xor(bk, m, 64);
      float os = __shfl_xor(s, m, 64);
      if (ob < b || (ob == b && obk < bk)) { s = fminf(b, os); b = ob; bk = obk; }
      else { s = fminf(ob, s); }
    }
    if (kg == 0 && p < N) {
      int bl = bk;
      if (s - b < MARGIN) {   // near-tie: decide in fp64 (fixed order, matches np)
        const float4* xrp = (const float4*)(X + (size_t)p * Dm);
        double bestd = 1e300; int bld = 0;
        for (int k = 0; k < Kc; ++k) {
          double a0 = 0, a1 = 0, a2 = 0, a3 = 0;
          const double* cp = Cd + (size_t)k * Dm;
#pragma unroll
          for (int q = 0; q < D4; ++q) {
            float4 xv = xrp[q];
            a0 += (double)xv.x * cp[4*q+0]; a1 += (double)xv.y * cp[4*q+1];
            a2 += (double)xv.z * cp[4*q+2]; a3 += (double)xv.w * cp[4*q+3];
          }
          double sc = c2d[k] - 2.0 * ((a0 + a1) + (a2 + a3));
          if (sc < bestd) { bestd = sc; bld = k; }   // strict < => first index
        }
        bl = bld;
      }
      lbl[p] = (unsigned char)bl;
    }
  }
}

// streaming gather-sum: block = slice of `chunk` consecutive rows; 4 waves =
// {row parity} x {dim half}; LDS fp64 accumulators per parity. Every row is
// processed in ascending order by a fixed wave -> deterministic, coalesced.
__global__ __launch_bounds__(256) void k_sum(
    const float* __restrict__ X, const unsigned char* __restrict__ lbl,
    double* __restrict__ spart, int* __restrict__ cpart,
    const int* __restrict__ done_flag, int N, int chunk) {
  if (*done_flag) return;
  __shared__ double acc[2][Kc * Dm];     // 128 KB: [parity][k*128+d]
  __shared__ unsigned int sl[1024];      // chunk <= 4096 labels
  __shared__ int cnt[Kc];
  const int tid = threadIdx.x;
  const int s = blockIdx.x;
  const int n0 = s * chunk;
  const int nrows = (N - n0 < chunk) ? (N - n0) : chunk;
  for (int e = tid; e < 2 * Kc * Dm; e += 256) ((double*)acc)[e] = 0.0;
  if (tid < Kc) cnt[tid] = 0;
  const int nw = (nrows > 0) ? ((nrows + 3) >> 2) : 0;
  const unsigned int* lw = (const unsigned int*)(lbl + n0);
  for (int w = tid; w < nw; w += 256) sl[w] = lw[w];
  __syncthreads();
  // histogram (integer atomics: order-independent, deterministic)
  for (int i = tid; i < nrows; i += 256)
    atomicAdd(&cnt[(sl[i >> 2] >> ((i & 3) * 8)) & 255], 1);
  // main accumulate
  const int w = tid >> 6, L = tid & 63;
  const int parity = w >> 1, half = w & 1;
  double* ac = acc[parity] + half * 64 + L;
  const float* Xb = X + (size_t)n0 * Dm + half * 64 + L;
  for (int i = parity; i < nrows; i += 2) {
    const int c = (sl[i >> 2] >> ((i & 3) * 8)) & 255;
    ac[c * Dm] += (double)Xb[(size_t)i * Dm];
  }
  __syncthreads();
  for (int e = tid; e < Kc * Dm; e += 256)
    spart[(size_t)s * (Kc * Dm) + e] = acc[0][e] + acc[1][e];   // fixed combine order
  if (tid < Kc) cpart[s * Kc + tid] = cnt[tid];
}

// per-cluster reduce over slices (fixed ascending order) + mean/shift/c2
__global__ __launch_bounds__(128) void k_update1(
    float* __restrict__ Cout, double* __restrict__ Cd,
    double* __restrict__ c2d, float* __restrict__ c2f,
    const double* __restrict__ spart, const int* __restrict__ cpart,
    double* __restrict__ shiftk, int* __restrict__ empty,
    const int* __restrict__ done_flag, int nslc) {
  if (*done_flag) return;
  __shared__ double red[128];
  __shared__ int ired[128];
  const int k = blockIdx.x, d = threadIdx.x;
  int c = 0;
  for (int s = d; s < nslc; s += 128) c += cpart[s * Kc + k];
  ired[d] = c; __syncthreads();
  for (int t = 64; t; t >>= 1) { if (d < t) ired[d] += ired[d + t]; __syncthreads(); }
  const int cnt = ired[0];
  double sum = 0.0;
#pragma unroll 8
  for (int s = 0; s < nslc; ++s) sum += spart[(size_t)s * (Kc * Dm) + k * Dm + d];
  const double mean = sum / (double)(cnt > 1 ? cnt : 1);
  const double oldv = Cd[k * Dm + d];
  Cd[k * Dm + d] = mean; Cout[k * Dm + d] = (float)mean;
  red[d] = (cnt != 0) ? (mean - oldv) * (mean - oldv) : 0.0;
  __syncthreads();
  for (int t = 64; t; t >>= 1) { if (d < t) red[d] += red[d + t]; __syncthreads(); }
  if (d == 0) shiftk[k] = red[0];
  __syncthreads();
  red[d] = mean * mean; __syncthreads();
  for (int t = 64; t; t >>= 1) { if (d < t) red[d] += red[d + t]; __syncthreads(); }
  if (d == 0) { c2d[k] = red[0]; c2f[k] = (float)red[0]; empty[k] = (cnt == 0); }
}

__global__ void k_update2(const double* __restrict__ shiftk, const int* __restrict__ empty,
                          int* __restrict__ done_flag, int* __restrict__ has_empty) {
  if (*done_flag) return;
  if (threadIdx.x == 0) {
    double sh = 0.0; int any = 0;
    for (int k = 0; k < Kc; ++k) { sh += shiftk[k]; any |= empty[k]; }   // fixed order
    *has_empty = any;
    if (!any && sh <= TOLd) *done_flag = 1;
  }
}

__global__ __launch_bounds__(BT) void k_far(
    const float* __restrict__ X, const double* __restrict__ Cd,
    const double* __restrict__ c2d, const double* __restrict__ x2d,
    const int* __restrict__ done_flag, const int* __restrict__ has_empty,
    const int* __restrict__ empty,
    double* __restrict__ opd, int* __restrict__ opi, int N) {
  if (*done_flag || !*has_empty) return;   // usual case: ~free
  __shared__ int semp[Kc];
  __shared__ double wd[4]; __shared__ int wi[4];
  if ((int)threadIdx.x < Kc) semp[threadIdx.x] = empty[threadIdx.x];
  __syncthreads();
  const int n = blockIdx.x * BT + threadIdx.x;
  double bd = -1.0; int bi = 0x7fffffff;
  if (n < N) {
    const float4* xr = (const float4*)(X + (size_t)n * Dm);
    float4 xv[D4];
#pragma unroll
    for (int q = 0; q < D4; ++q) xv[q] = xr[q];
    double md = 1e300;
    for (int k = 0; k < Kc; ++k) {
      if (semp[k]) continue;
      double a0 = 0, a1 = 0, a2 = 0, a3 = 0;
      const double* cp = Cd + (size_t)k * Dm;
#pragma unroll
      for (int q = 0; q < D4; ++q) {
        a0 += (double)xv[q].x * cp[4*q+0]; a1 += (double)xv[q].y * cp[4*q+1];
        a2 += (double)xv[q].z * cp[4*q+2]; a3 += (double)xv[q].w * cp[4*q+3];
      }
      double d2v = c2d[k] + x2d[n] - 2.0 * ((a0 + a1) + (a2 + a3));
      if (d2v < 0.0) d2v = 0.0;
      if (d2v < md) md = d2v;
    }
    bd = md; bi = n;
  }
  block_argmax(bd, bi, wd, wi);
  if (threadIdx.x == 0) { opd[blockIdx.x] = bd; opi[blockIdx.x] = bi; }
}

__global__ __launch_bounds__(BT) void k_fix(
    const float* __restrict__ X, float* __restrict__ Cout, double* __restrict__ Cd,
    double* __restrict__ c2d, float* __restrict__ c2f,
    const int* __restrict__ done_flag, const int* __restrict__ has_empty,
    const int* __restrict__ empty,
    const double* __restrict__ ipd, const int* __restrict__ ipi, int nparts) {
  if (*done_flag || !*has_empty) return;
  const int lane = threadIdx.x & 63;
  double bd = -1.0; int bi = 0x7fffffff;
  for (int t = lane; t < nparts; t += 64) {
    double d = ipd[t]; int id = ipi[t];
    if (d > bd || (d == bd && id < bi)) { bd = d; bi = id; }
  }
  wave_argmax(bd, bi);
  const int far = __shfl(bi, 0, 64);
  for (int e = threadIdx.x; e < Kc * Dm; e += BT) {
    if (empty[e >> 7]) {
      float v = X[(size_t)far * Dm + (e & 127)];
      Cout[e] = v; Cd[e] = (double)v;
    }
  }
  __syncthreads();
  if ((int)threadIdx.x < Kc && empty[threadIdx.x]) {
    double s2 = 0.0;
    for (int d = 0; d < Dm; ++d) { double v = Cd[(size_t)threadIdx.x * Dm + d]; s2 += v * v; }
    c2d[threadIdx.x] = s2; c2f[threadIdx.x] = (float)s2;
  }
}

extern "C" void kernel_launch(void* const* d_in, const int* in_sizes, int n_in,
                              void* d_out, int out_size, void* d_ws, size_t ws_size,
                              hipStream_t stream) {
  const float* X = (const float*)d_in[0];
  const int N = in_sizes[0] / Dm;          // 200000
  float* Cout = (float*)d_out;             // (64,128) fp32 — fp32 shadow of Cd
  (void)ws_size; (void)n_in; (void)out_size;

  char* w = (char*)d_ws;
  auto alloc = [&](size_t bytes) -> void* {
    void* p = (void*)w; w += (bytes + 255) & ~(size_t)255; return p;
  };
  const size_t NP = ((size_t)N + 255) & ~(size_t)255;
  const int IB = (N + BT - 1) / BT;        // 782 blocks, one point per thread
  const int AB = (N + PPB - 1) / PPB;      // 1563 assign blocks
  double* x2d  = (double*)alloc(NP * 8);
  // mind (init-only) and spart (Lloyd-only) are disjoint in time -> union
  const size_t spart_bytes = (size_t)SLC * Kc * Dm * 8;   // 16.8 MB
  const size_t union_bytes = (spart_bytes > NP * 8) ? spart_bytes : NP * 8;
  double* mind  = (double*)alloc(union_bytes);
  double* spart = mind;
  double* pd0  = (double*)alloc(1024 * 8);
  double* pd1  = (double*)alloc(1024 * 8);
  int*    pi0  = (int*)alloc(1024 * 4);
  int*    pi1  = (int*)alloc(1024 * 4);
  double* Cd   = (double*)alloc((size_t)Kc * Dm * 8);
  double* c2d  = (double*)alloc(Kc * 8);
  float*  c2f  = (float*)alloc(Kc * 4);
  int*    cpart = (int*)alloc(SLC * Kc * 4);
  double* shiftk = (double*)alloc(Kc * 8);
  unsigned char* lbl = (unsigned char*)alloc(NP);
  int*    done  = (int*)alloc(4);
  int*    hasem = (int*)alloc(4);
  int*    empty = (int*)alloc(Kc * 4);

  double* pd[2] = {pd0, pd1};
  int*    pi[2] = {pi0, pi1};

  // ---- farthest-point init: C[0]=X[0], then 63 sequential argmax picks (all fp64) ----
  k_init_first<<<IB, BT, 0, stream>>>(X, Cout, Cd, x2d, mind, pd[0], pi[0], done, N);
  for (int i = 1; i <= 63; ++i) {
    const int rb = (i + 1) & 1, wb = i & 1;   // double-buffered partials
    if (i < 63) {
      k_init_step<<<IB, BT, 0, stream>>>(X, Cout, Cd, x2d, mind, pd[rb], pi[rb],
                                         pd[wb], pi[wb], N, IB, i, 1, nullptr, nullptr);
    } else {
      k_init_step<<<1, BT, 0, stream>>>(X, Cout, Cd, x2d, mind, pd[rb], pi[rb],
                                        pd[wb], pi[wb], N, IB, i, 0, c2d, c2f);
    }
  }

  // ---- 10 Lloyd iterations ----
  const int chunk = ((N + SLC - 1) / SLC + 3) & ~3;   // 784, multiple of 4
  for (int it = 0; it < NITER; ++it) {
    k_assign<<<AB, 256, 0, stream>>>(X, Cout, c2f, Cd, c2d, lbl, done, N);
    k_sum<<<SLC, 256, 0, stream>>>(X, lbl, spart, cpart, done, N, chunk);
    k_update1<<<Kc, 128, 0, stream>>>(Cout, Cd, c2d, c2f, spart, cpart,
                                      shiftk, empty, done, SLC);
    k_update2<<<1, 64, 0, stream>>>(shiftk, empty, done, hasem);
    k_far<<<IB, BT, 0, stream>>>(X, Cd, c2d, x2d, done, hasem, empty, pd[0], pi[0], N);
    k_fix<<<1, BT, 0, stream>>>(X, Cout, Cd, c2d, c2f, done, hasem, empty, pd[0], pi[0], IB);
  }
}

// Round 6
// 6181.741 us; speedup vs baseline: 1.9873x; 1.9873x over previous
//
#include <hip/hip_runtime.h>

constexpr int Dm = 128;     // dims
constexpr int D4 = 32;      // dims/4
constexpr int Kc = 64;      // clusters
constexpr int NITER = 10;
constexpr double TOLd = 1e-4;
constexpr int BT  = 256;
constexpr int SLC = 256;    // slices for gather-sum (1 block/CU, 128KB LDS acc)
constexpr float MARGIN = 1e-2f;   // fp32 top-2 gap below which fp64 re-check (k_tie)

// ---- argmax helpers: exact total order (value desc, index asc) => deterministic ----
__device__ __forceinline__ void wave_argmax(double& bd, int& bi) {
#pragma unroll
  for (int off = 32; off; off >>= 1) {
    double od = __shfl_down(bd, (unsigned)off, 64);
    int    oi = __shfl_down(bi, (unsigned)off, 64);
    if (od > bd || (od == bd && oi < bi)) { bd = od; bi = oi; }
  }
}

// 256-thread block argmax; wd/wi are 4-entry LDS scratch
__device__ __forceinline__ void block_argmax(double& bd, int& bi, double* wd, int* wi) {
  wave_argmax(bd, bi);
  const int w = threadIdx.x >> 6;
  if ((threadIdx.x & 63) == 0) { wd[w] = bd; wi[w] = bi; }
  __syncthreads();
  bd = wd[0]; bi = wi[0];
#pragma unroll
  for (int j = 1; j < 4; ++j) {
    double od = wd[j]; int oi = wi[j];
    if (od > bd || (od == bd && oi < bi)) { bd = od; bi = oi; }
  }
  __syncthreads();
}

__global__ __launch_bounds__(BT) void k_init_first(
    const float* __restrict__ X, float* __restrict__ Cout, double* __restrict__ Cd,
    double* __restrict__ x2d, double* __restrict__ mind,
    double* __restrict__ opd, int* __restrict__ opi, int* __restrict__ done_flag, int N) {
  __shared__ double cent[Dm];
  __shared__ double wd[4]; __shared__ int wi[4];
  if (threadIdx.x < Dm) cent[threadIdx.x] = (double)X[threadIdx.x];
  if (blockIdx.x == 0) {
    if (threadIdx.x == 0) *done_flag = 0;
    if (threadIdx.x < Dm) {
      Cout[threadIdx.x] = X[threadIdx.x];
      Cd[threadIdx.x]   = (double)X[threadIdx.x];
    }
  }
  __syncthreads();
  double c2 = 0.0;
  for (int d = 0; d < Dm; ++d) c2 += cent[d] * cent[d];
  const int n = blockIdx.x * BT + threadIdx.x;
  double bd = -1.0; int bi = 0x7fffffff;
  if (n < N) {
    const float4* xr = (const float4*)(X + (size_t)n * Dm);
    double a0 = 0, a1 = 0, a2 = 0, a3 = 0;
    double x0 = 0, x1 = 0, x2 = 0, x3 = 0;
#pragma unroll 8
    for (int q = 0; q < D4; ++q) {
      float4 xv = xr[q];
      a0 += (double)xv.x * cent[4*q+0]; a1 += (double)xv.y * cent[4*q+1];
      a2 += (double)xv.z * cent[4*q+2]; a3 += (double)xv.w * cent[4*q+3];
      x0 += (double)xv.x * xv.x; x1 += (double)xv.y * xv.y;
      x2 += (double)xv.z * xv.z; x3 += (double)xv.w * xv.w;
    }
    double xx  = (x0 + x1) + (x2 + x3);
    double dot = (a0 + a1) + (a2 + a3);
    x2d[n] = xx;
    double d2 = c2 + xx - 2.0 * dot; if (d2 < 0.0) d2 = 0.0;
    mind[n] = d2;
    bd = d2; bi = n;
  }
  block_argmax(bd, bi, wd, wi);
  if (threadIdx.x == 0) { opd[blockIdx.x] = bd; opi[blockIdx.x] = bi; }
}

__global__ __launch_bounds__(BT) void k_init_step(
    const float* __restrict__ X, float* __restrict__ Cout, double* __restrict__ Cd,
    const double* __restrict__ x2d, double* __restrict__ mind,
    const double* __restrict__ ipd, const int* __restrict__ ipi,
    double* __restrict__ opd, int* __restrict__ opi,
    int N, int nparts, int ci, int update,
    double* __restrict__ c2d, float* __restrict__ c2f, int* __restrict__ tie_cnt) {
  __shared__ double cent[Dm];
  __shared__ double wd[4]; __shared__ int wi[4];
  // per-wave redundant partial reduce (no barriers, exact total order)
  const int lane = threadIdx.x & 63;
  double bd = -1.0; int bi = 0x7fffffff;
  for (int t = lane; t < nparts; t += 64) {
    double d = ipd[t]; int id = ipi[t];
    if (d > bd || (d == bd && id < bi)) { bd = d; bi = id; }
  }
  wave_argmax(bd, bi);
  const int idx = __shfl(bi, 0, 64);
  if (threadIdx.x < Dm) {
    float xv = X[(size_t)idx * Dm + threadIdx.x];
    cent[threadIdx.x] = (double)xv;
    if (blockIdx.x == 0) {
      Cout[(size_t)ci * Dm + threadIdx.x] = xv;
      Cd[(size_t)ci * Dm + threadIdx.x]   = (double)xv;
    }
  }
  __syncthreads();
  if (c2d) {  // final step (single block): c2 of all rows for the Lloyd loop
    if ((int)threadIdx.x < Kc) {
      double s = 0.0;
      if ((int)threadIdx.x == ci) { for (int d = 0; d < Dm; ++d) s += cent[d] * cent[d]; }
      else { for (int d = 0; d < Dm; ++d) { double v = Cd[(size_t)threadIdx.x * Dm + d]; s += v * v; } }
      c2d[threadIdx.x] = s; c2f[threadIdx.x] = (float)s;
    }
    if (threadIdx.x == 0 && tie_cnt) *tie_cnt = 0;
  }
  if (!update) return;
  double c2 = 0.0;
  for (int d = 0; d < Dm; ++d) c2 += cent[d] * cent[d];
  const int n = blockIdx.x * BT + threadIdx.x;
  bd = -1.0; bi = 0x7fffffff;
  if (n < N) {
    const float4* xr = (const float4*)(X + (size_t)n * Dm);
    double a0 = 0, a1 = 0, a2 = 0, a3 = 0;
#pragma unroll 8
    for (int q = 0; q < D4; ++q) {
      float4 xv = xr[q];
      a0 += (double)xv.x * cent[4*q+0]; a1 += (double)xv.y * cent[4*q+1];
      a2 += (double)xv.z * cent[4*q+2]; a3 += (double)xv.w * cent[4*q+3];
    }
    double dot = (a0 + a1) + (a2 + a3);
    double d2 = c2 + x2d[n] - 2.0 * dot; if (d2 < 0.0) d2 = 0.0;
    double m = mind[n]; if (d2 < m) m = d2;
    mind[n] = m;
    bd = m; bi = n;
  }
  block_argmax(bd, bi, wd, wi);
  if (threadIdx.x == 0) { opd[blockIdx.x] = bd; opi[blockIdx.x] = bi; }
}

// fp32 screen (R4 structure): one point/thread, row in regs, LDS C broadcast.
// Near-ties (fp32 top-2 gap < MARGIN) are appended to tie_list for k_tie.
__global__ __launch_bounds__(BT) void k_assign(
    const float* __restrict__ X, const float* __restrict__ Cf,
    const float* __restrict__ c2f,
    unsigned char* __restrict__ lbl,
    int* __restrict__ tie_list, int* __restrict__ tie_cnt,
    const int* __restrict__ done_flag, int N) {
  if (*done_flag) return;
  __shared__ float4 cs[Kc * D4];   // 32 KB fp32 centroids
  __shared__ float c2s[Kc];
  for (int e = threadIdx.x; e < Kc * D4; e += BT) cs[e] = ((const float4*)Cf)[e];
  if ((int)threadIdx.x < Kc) c2s[threadIdx.x] = c2f[threadIdx.x];
  __syncthreads();
  const int n = blockIdx.x * BT + threadIdx.x;
  if (n >= N) return;
  float4 xv[D4];
  const float4* xr = (const float4*)(X + (size_t)n * Dm);
#pragma unroll
  for (int q = 0; q < D4; ++q) xv[q] = xr[q];
  // fp32 pass with top-2 tracking (x2 cancels in the argmin -> score = c2 - 2*dot)
  float best = 3.4028235e38f, second = 3.4028235e38f; int bl = 0;
  for (int k = 0; k < Kc; ++k) {
    float a0 = 0, a1 = 0, a2 = 0, a3 = 0;
#pragma unroll
    for (int q = 0; q < D4; ++q) {
      float4 cv = cs[k * D4 + q];
      a0 += xv[q].x * cv.x; a1 += xv[q].y * cv.y;
      a2 += xv[q].z * cv.z; a3 += xv[q].w * cv.w;
    }
    float sc = c2s[k] - 2.f * ((a0 + a1) + (a2 + a3));
    if (sc < best) { second = best; best = sc; bl = k; }
    else if (sc < second) second = sc;
  }
  lbl[n] = (unsigned char)bl;
  if (second - best < MARGIN) {          // rare (~0.3%): defer to wave-parallel fp64
    int t = atomicAdd(tie_cnt, 1);
    tie_list[t] = n;
  }
}

// fp64 tie resolution: one WAVE per tie point; lane = cluster. Same 4-accumulator
// summation order as the reference path; lexicographic (score asc, k asc) argmin.
__global__ __launch_bounds__(256) void k_tie(
    const float* __restrict__ X, const double* __restrict__ Cd,
    const double* __restrict__ c2d,
    const int* __restrict__ tie_list, const int* __restrict__ tie_cnt,
    unsigned char* __restrict__ lbl, const int* __restrict__ done_flag) {
  if (*done_flag) return;
  const int nt = *tie_cnt;
  const int gw = (int)((blockIdx.x * 256 + threadIdx.x) >> 6);
  const int lane = threadIdx.x & 63;
  const int nwaves = gridDim.x * 4;
  const double* cp = Cd + (size_t)lane * Dm;
  const double myc2 = c2d[lane];
  for (int t = gw; t < nt; t += nwaves) {
    const int n = tie_list[t];
    const float4* xr = (const float4*)(X + (size_t)n * Dm);
    double a0 = 0, a1 = 0, a2 = 0, a3 = 0;
#pragma unroll 8
    for (int q = 0; q < D4; ++q) {
      float4 xv = xr[q];   // broadcast load (same addr all lanes)
      a0 += (double)xv.x * cp[4*q+0]; a1 += (double)xv.y * cp[4*q+1];
      a2 += (double)xv.z * cp[4*q+2]; a3 += (double)xv.w * cp[4*q+3];
    }
    double sc = myc2 - 2.0 * ((a0 + a1) + (a2 + a3));
    int bk = lane;
#pragma unroll
    for (int off = 32; off; off >>= 1) {
      double osc = __shfl_down(sc, (unsigned)off, 64);
      int    obk = __shfl_down(bk, (unsigned)off, 64);
      if (osc < sc || (osc == sc && obk < bk)) { sc = osc; bk = obk; }
    }
    if (lane == 0) lbl[n] = (unsigned char)bk;
  }
}

// streaming gather-sum: block = slice of `chunk` consecutive rows; 4 waves =
// {row parity} x {dim half}; LDS fp64 accumulators per parity. Every row is
// processed in ascending order by a fixed wave -> deterministic, coalesced.
__global__ __launch_bounds__(256) void k_sum(
    const float* __restrict__ X, const unsigned char* __restrict__ lbl,
    double* __restrict__ spart, int* __restrict__ cpart,
    const int* __restrict__ done_flag, int N, int chunk) {
  if (*done_flag) return;
  __shared__ double acc[2][Kc * Dm];     // 128 KB: [parity][k*128+d]
  __shared__ unsigned int sl[1024];      // chunk <= 4096 labels
  __shared__ int cnt[Kc];
  const int tid = threadIdx.x;
  const int s = blockIdx.x;
  const int n0 = s * chunk;
  const int nrows = (N - n0 < chunk) ? (N - n0) : chunk;
  for (int e = tid; e < 2 * Kc * Dm; e += 256) ((double*)acc)[e] = 0.0;
  if (tid < Kc) cnt[tid] = 0;
  const int nw = (nrows > 0) ? ((nrows + 3) >> 2) : 0;
  const unsigned int* lw = (const unsigned int*)(lbl + n0);
  for (int w = tid; w < nw; w += 256) sl[w] = lw[w];
  __syncthreads();
  // histogram (integer atomics: order-independent, deterministic)
  for (int i = tid; i < nrows; i += 256)
    atomicAdd(&cnt[(sl[i >> 2] >> ((i & 3) * 8)) & 255], 1);
  // main accumulate
  const int w = tid >> 6, L = tid & 63;
  const int parity = w >> 1, half = w & 1;
  double* ac = acc[parity] + half * 64 + L;
  const float* Xb = X + (size_t)n0 * Dm + half * 64 + L;
  for (int i = parity; i < nrows; i += 2) {
    const int c = (sl[i >> 2] >> ((i & 3) * 8)) & 255;
    ac[c * Dm] += (double)Xb[(size_t)i * Dm];
  }
  __syncthreads();
  for (int e = tid; e < Kc * Dm; e += 256)
    spart[(size_t)s * (Kc * Dm) + e] = acc[0][e] + acc[1][e];   // fixed combine order
  if (tid < Kc) cpart[s * Kc + tid] = cnt[tid];
}

// per-cluster reduce over slices (fixed ascending order) + mean/shift/c2
__global__ __launch_bounds__(128) void k_update1(
    float* __restrict__ Cout, double* __restrict__ Cd,
    double* __restrict__ c2d, float* __restrict__ c2f,
    const double* __restrict__ spart, const int* __restrict__ cpart,
    double* __restrict__ shiftk, int* __restrict__ empty,
    const int* __restrict__ done_flag, int nslc) {
  if (*done_flag) return;
  __shared__ double red[128];
  __shared__ int ired[128];
  const int k = blockIdx.x, d = threadIdx.x;
  int c = 0;
  for (int s = d; s < nslc; s += 128) c += cpart[s * Kc + k];
  ired[d] = c; __syncthreads();
  for (int t = 64; t; t >>= 1) { if (d < t) ired[d] += ired[d + t]; __syncthreads(); }
  const int cnt = ired[0];
  double sum = 0.0;
#pragma unroll 8
  for (int s = 0; s < nslc; ++s) sum += spart[(size_t)s * (Kc * Dm) + k * Dm + d];
  const double mean = sum / (double)(cnt > 1 ? cnt : 1);
  const double oldv = Cd[k * Dm + d];
  Cd[k * Dm + d] = mean; Cout[k * Dm + d] = (float)mean;
  red[d] = (cnt != 0) ? (mean - oldv) * (mean - oldv) : 0.0;
  __syncthreads();
  for (int t = 64; t; t >>= 1) { if (d < t) red[d] += red[d + t]; __syncthreads(); }
  if (d == 0) shiftk[k] = red[0];
  __syncthreads();
  red[d] = mean * mean; __syncthreads();
  for (int t = 64; t; t >>= 1) { if (d < t) red[d] += red[d + t]; __syncthreads(); }
  if (d == 0) { c2d[k] = red[0]; c2f[k] = (float)red[0]; empty[k] = (cnt == 0); }
}

__global__ void k_update2(const double* __restrict__ shiftk, const int* __restrict__ empty,
                          int* __restrict__ done_flag, int* __restrict__ has_empty,
                          int* __restrict__ tie_cnt) {
  if (*done_flag) return;
  if (threadIdx.x == 0) {
    double sh = 0.0; int any = 0;
    for (int k = 0; k < Kc; ++k) { sh += shiftk[k]; any |= empty[k]; }   // fixed order
    *has_empty = any;
    *tie_cnt = 0;   // reset for next iteration's assign
    if (!any && sh <= TOLd) *done_flag = 1;
  }
}

__global__ __launch_bounds__(BT) void k_far(
    const float* __restrict__ X, const double* __restrict__ Cd,
    const double* __restrict__ c2d, const double* __restrict__ x2d,
    const int* __restrict__ done_flag, const int* __restrict__ has_empty,
    const int* __restrict__ empty,
    double* __restrict__ opd, int* __restrict__ opi, int N) {
  if (*done_flag || !*has_empty) return;   // usual case: ~free
  __shared__ int semp[Kc];
  __shared__ double wd[4]; __shared__ int wi[4];
  if ((int)threadIdx.x < Kc) semp[threadIdx.x] = empty[threadIdx.x];
  __syncthreads();
  const int n = blockIdx.x * BT + threadIdx.x;
  double bd = -1.0; int bi = 0x7fffffff;
  if (n < N) {
    const float4* xr = (const float4*)(X + (size_t)n * Dm);
    float4 xv[D4];
#pragma unroll
    for (int q = 0; q < D4; ++q) xv[q] = xr[q];
    double md = 1e300;
    for (int k = 0; k < Kc; ++k) {
      if (semp[k]) continue;
      double a0 = 0, a1 = 0, a2 = 0, a3 = 0;
      const double* cp = Cd + (size_t)k * Dm;
#pragma unroll
      for (int q = 0; q < D4; ++q) {
        a0 += (double)xv[q].x * cp[4*q+0]; a1 += (double)xv[q].y * cp[4*q+1];
        a2 += (double)xv[q].z * cp[4*q+2]; a3 += (double)xv[q].w * cp[4*q+3];
      }
      double d2v = c2d[k] + x2d[n] - 2.0 * ((a0 + a1) + (a2 + a3));
      if (d2v < 0.0) d2v = 0.0;
      if (d2v < md) md = d2v;
    }
    bd = md; bi = n;
  }
  block_argmax(bd, bi, wd, wi);
  if (threadIdx.x == 0) { opd[blockIdx.x] = bd; opi[blockIdx.x] = bi; }
}

__global__ __launch_bounds__(BT) void k_fix(
    const float* __restrict__ X, float* __restrict__ Cout, double* __restrict__ Cd,
    double* __restrict__ c2d, float* __restrict__ c2f,
    const int* __restrict__ done_flag, const int* __restrict__ has_empty,
    const int* __restrict__ empty,
    const double* __restrict__ ipd, const int* __restrict__ ipi, int nparts) {
  if (*done_flag || !*has_empty) return;
  const int lane = threadIdx.x & 63;
  double bd = -1.0; int bi = 0x7fffffff;
  for (int t = lane; t < nparts; t += 64) {
    double d = ipd[t]; int id = ipi[t];
    if (d > bd || (d == bd && id < bi)) { bd = d; bi = id; }
  }
  wave_argmax(bd, bi);
  const int far = __shfl(bi, 0, 64);
  for (int e = threadIdx.x; e < Kc * Dm; e += BT) {
    if (empty[e >> 7]) {
      float v = X[(size_t)far * Dm + (e & 127)];
      Cout[e] = v; Cd[e] = (double)v;
    }
  }
  __syncthreads();
  if ((int)threadIdx.x < Kc && empty[threadIdx.x]) {
    double s2 = 0.0;
    for (int d = 0; d < Dm; ++d) { double v = Cd[(size_t)threadIdx.x * Dm + d]; s2 += v * v; }
    c2d[threadIdx.x] = s2; c2f[threadIdx.x] = (float)s2;
  }
}

extern "C" void kernel_launch(void* const* d_in, const int* in_sizes, int n_in,
                              void* d_out, int out_size, void* d_ws, size_t ws_size,
                              hipStream_t stream) {
  const float* X = (const float*)d_in[0];
  const int N = in_sizes[0] / Dm;          // 200000
  float* Cout = (float*)d_out;             // (64,128) fp32 — fp32 shadow of Cd
  (void)ws_size; (void)n_in; (void)out_size;

  char* w = (char*)d_ws;
  auto alloc = [&](size_t bytes) -> void* {
    void* p = (void*)w; w += (bytes + 255) & ~(size_t)255; return p;
  };
  const size_t NP = ((size_t)N + 255) & ~(size_t)255;
  const int IB = (N + BT - 1) / BT;        // 782 blocks, one point per thread
  double* x2d  = (double*)alloc(NP * 8);
  // mind (init-only) and spart (Lloyd-only) are disjoint in time -> union
  const size_t spart_bytes = (size_t)SLC * Kc * Dm * 8;   // 16.8 MB
  const size_t union_bytes = (spart_bytes > NP * 8) ? spart_bytes : NP * 8;
  double* mind  = (double*)alloc(union_bytes);
  double* spart = mind;
  double* pd0  = (double*)alloc(1024 * 8);
  double* pd1  = (double*)alloc(1024 * 8);
  int*    pi0  = (int*)alloc(1024 * 4);
  int*    pi1  = (int*)alloc(1024 * 4);
  double* Cd   = (double*)alloc((size_t)Kc * Dm * 8);
  double* c2d  = (double*)alloc(Kc * 8);
  float*  c2f  = (float*)alloc(Kc * 4);
  int*    cpart = (int*)alloc(SLC * Kc * 4);
  double* shiftk = (double*)alloc(Kc * 8);
  unsigned char* lbl = (unsigned char*)alloc(NP);
  int*    tie_list = (int*)alloc(NP * 4);
  int*    tie_cnt  = (int*)alloc(4);
  int*    done  = (int*)alloc(4);
  int*    hasem = (int*)alloc(4);
  int*    empty = (int*)alloc(Kc * 4);

  double* pd[2] = {pd0, pd1};
  int*    pi[2] = {pi0, pi1};

  // ---- farthest-point init: C[0]=X[0], then 63 sequential argmax picks (all fp64) ----
  k_init_first<<<IB, BT, 0, stream>>>(X, Cout, Cd, x2d, mind, pd[0], pi[0], done, N);
  for (int i = 1; i <= 63; ++i) {
    const int rb = (i + 1) & 1, wb = i & 1;   // double-buffered partials
    if (i < 63) {
      k_init_step<<<IB, BT, 0, stream>>>(X, Cout, Cd, x2d, mind, pd[rb], pi[rb],
                                         pd[wb], pi[wb], N, IB, i, 1,
                                         nullptr, nullptr, nullptr);
    } else {
      k_init_step<<<1, BT, 0, stream>>>(X, Cout, Cd, x2d, mind, pd[rb], pi[rb],
                                        pd[wb], pi[wb], N, IB, i, 0,
                                        c2d, c2f, tie_cnt);
    }
  }

  // ---- 10 Lloyd iterations ----
  const int chunk = ((N + SLC - 1) / SLC + 3) & ~3;   // 784, multiple of 4
  for (int it = 0; it < NITER; ++it) {
    k_assign<<<IB, BT, 0, stream>>>(X, Cout, c2f, lbl, tie_list, tie_cnt, done, N);
    k_tie<<<128, 256, 0, stream>>>(X, Cd, c2d, tie_list, tie_cnt, lbl, done);
    k_sum<<<SLC, 256, 0, stream>>>(X, lbl, spart, cpart, done, N, chunk);
    k_update1<<<Kc, 128, 0, stream>>>(Cout, Cd, c2d, c2f, spart, cpart,
                                      shiftk, empty, done, SLC);
    k_update2<<<1, 64, 0, stream>>>(shiftk, empty, done, hasem, tie_cnt);
    k_far<<<IB, BT, 0, stream>>>(X, Cd, c2d, x2d, done, hasem, empty, pd[0], pi[0], N);
    k_fix<<<1, BT, 0, stream>>>(X, Cout, Cd, c2d, c2f, done, hasem, empty, pd[0], pi[0], IB);
  }
}